// Round 1
// baseline (1702.900 us; speedup 1.0000x reference)
//
#include <hip/hip_runtime.h>
#include <stdint.h>

// Problem constants (B=4, S=2048, K=4096, O=11008, G=128)
#define MDIM 8192   // B*S
#define NDIM 11008  // O
#define KDIM 4096   // K
#define GRP  128

typedef __attribute__((ext_vector_type(8))) __bf16 bf16x8;
typedef __attribute__((ext_vector_type(4))) float f32x4;
typedef __attribute__((ext_vector_type(4))) unsigned short u16x4;

static __device__ __forceinline__ unsigned short f2bf(float f) {
    // round-to-nearest-even fp32 -> bf16 (no NaN inputs in this problem)
    union { float f; unsigned int u; } c; c.f = f;
    unsigned int u = c.u;
    u += 0x7fffu + ((u >> 16) & 1u);
    return (unsigned short)(u >> 16);
}

// ---------------------------------------------------------------------------
// Kernel 1: dynamic per-row activation quant -> dequantized bf16
// one block (256 thr) per row of x (8192 rows, K=4096; 16 elems/thread)
// ---------------------------------------------------------------------------
__global__ __launch_bounds__(256) void quant_x_kernel(const float* __restrict__ x,
                                                      unsigned short* __restrict__ xq) {
    __shared__ float red[256];
    const int row = blockIdx.x;
    const int tid = threadIdx.x;
    const float* xr = x + (size_t)row * KDIM;

    f32x4 v[4];
    float amax = 0.f;
#pragma unroll
    for (int i = 0; i < 4; ++i) {
        v[i] = *(const f32x4*)(xr + 4 * (tid + 256 * i));
        amax = fmaxf(amax, fmaxf(fmaxf(fabsf(v[i].x), fabsf(v[i].y)),
                                 fmaxf(fabsf(v[i].z), fabsf(v[i].w))));
    }
    red[tid] = amax;
    __syncthreads();
    for (int s = 128; s > 0; s >>= 1) {
        if (tid < s) red[tid] = fmaxf(red[tid], red[tid + s]);
        __syncthreads();
    }
    const float scale = fmaxf(red[0], 1e-5f) / 127.0f;  // matches ref: max(amax,1e-5)/127

#pragma unroll
    for (int i = 0; i < 4; ++i) {
        u16x4 ov;
        float q;
        q = fminf(fmaxf(rintf(v[i].x / scale), -128.f), 127.f); ov.x = f2bf(q * scale);
        q = fminf(fmaxf(rintf(v[i].y / scale), -128.f), 127.f); ov.y = f2bf(q * scale);
        q = fminf(fmaxf(rintf(v[i].z / scale), -128.f), 127.f); ov.z = f2bf(q * scale);
        q = fminf(fmaxf(rintf(v[i].w / scale), -128.f), 127.f); ov.w = f2bf(q * scale);
        *(u16x4*)(xq + (size_t)row * KDIM + 4 * (tid + 256 * i)) = ov;
    }
}

// ---------------------------------------------------------------------------
// Kernel 2: int4-group weight dequant -> bf16 (O x K row-major = B^T layout)
// one thread per 4 consecutive k of one o. scales_and_zeros: (K/G, O, 2)
// ---------------------------------------------------------------------------
__global__ __launch_bounds__(256) void dequant_w_kernel(const int* __restrict__ w,
                                                        const float* __restrict__ sz,
                                                        unsigned short* __restrict__ wq) {
    const int idx = blockIdx.x * 256 + threadIdx.x;
    const int kc = idx & (KDIM / 4 - 1);  // 0..1023
    const int o  = idx >> 10;
    const int k0 = kc << 2;
    const int g  = k0 >> 7;               // k0 / 128
    const float2 szv = *(const float2*)(sz + ((size_t)g * NDIM + o) * 2);
    const float s = szv.x, z = szv.y;
    const int4 wv = *(const int4*)(w + (size_t)o * KDIM + k0);
    u16x4 ov;
    ov.x = f2bf(((float)wv.x - z) * s);
    ov.y = f2bf(((float)wv.y - z) * s);
    ov.z = f2bf(((float)wv.z - z) * s);
    ov.w = f2bf(((float)wv.w - z) * s);
    *(u16x4*)(wq + (size_t)o * KDIM + k0) = ov;
}

// ---------------------------------------------------------------------------
// Kernel 3: bf16 GEMM, C[M,N] = A[M,K] * B[N,K]^T  (m97 structure)
// 128x128 tile, BK=32, 256 thr = 4 waves in 2x2, each wave 64x64 via 4x4
// mfma_f32_16x16x32_bf16 frags. global_load_lds width-16 staging.
// ---------------------------------------------------------------------------
__global__ __launch_bounds__(256) void gemm_bt_kernel(const unsigned short* __restrict__ A,
                                                      const unsigned short* __restrict__ B,
                                                      float* __restrict__ C) {
    __shared__ unsigned short As[128 * 32];  // [m][k] row-major, 8 KB
    __shared__ unsigned short Bs[128 * 32];  // [n][k] row-major, 8 KB

    const int tid  = threadIdx.x;
    const int lane = tid & 63;
    const int wave = tid >> 6;
    const int quad = lane >> 4;
    const int l16  = lane & 15;
    const int bm = blockIdx.y * 128;
    const int bn = blockIdx.x * 128;
    const int wm = (wave >> 1) * 64;
    const int wn = (wave & 1) * 64;

    f32x4 acc[4][4];
#pragma unroll
    for (int i = 0; i < 4; ++i)
#pragma unroll
        for (int j = 0; j < 4; ++j) acc[i][j] = (f32x4){0.f, 0.f, 0.f, 0.f};

    // Staging: tile = 512 chunks of 16B; thread t owns chunks t and t+256.
    // chunk c -> row c>>2, k-offset (c&3)*8 elems. LDS byte offset = c*16
    // (contiguous in lane order -> satisfies global_load_lds wave-uniform-base rule).
    const int rlo = tid >> 2;            // 0..63
    const int kof = (tid & 3) * 8;
    const unsigned short* gA0 = A + (size_t)(bm + rlo) * KDIM + kof;
    const unsigned short* gA1 = A + (size_t)(bm + 64 + rlo) * KDIM + kof;
    const unsigned short* gB0 = B + (size_t)(bn + rlo) * KDIM + kof;
    const unsigned short* gB1 = B + (size_t)(bn + 64 + rlo) * KDIM + kof;
    unsigned short* lA0 = As + tid * 8;
    unsigned short* lA1 = As + (tid + 256) * 8;
    unsigned short* lB0 = Bs + tid * 8;
    unsigned short* lB1 = Bs + (tid + 256) * 8;

    for (int k0 = 0; k0 < KDIM; k0 += 32) {
        __syncthreads();
        __builtin_amdgcn_global_load_lds((const __attribute__((address_space(1))) void*)(gA0 + k0),
                                         (__attribute__((address_space(3))) void*)lA0, 16, 0, 0);
        __builtin_amdgcn_global_load_lds((const __attribute__((address_space(1))) void*)(gA1 + k0),
                                         (__attribute__((address_space(3))) void*)lA1, 16, 0, 0);
        __builtin_amdgcn_global_load_lds((const __attribute__((address_space(1))) void*)(gB0 + k0),
                                         (__attribute__((address_space(3))) void*)lB0, 16, 0, 0);
        __builtin_amdgcn_global_load_lds((const __attribute__((address_space(1))) void*)(gB1 + k0),
                                         (__attribute__((address_space(3))) void*)lB1, 16, 0, 0);
        __syncthreads();

        bf16x8 af[4], bfr[4];
#pragma unroll
        for (int i = 0; i < 4; ++i)
            af[i] = *(const bf16x8*)(As + (wm + i * 16 + l16) * 32 + quad * 8);
#pragma unroll
        for (int j = 0; j < 4; ++j)
            bfr[j] = *(const bf16x8*)(Bs + (wn + j * 16 + l16) * 32 + quad * 8);

#pragma unroll
        for (int i = 0; i < 4; ++i)
#pragma unroll
            for (int j = 0; j < 4; ++j)
                acc[i][j] = __builtin_amdgcn_mfma_f32_16x16x32_bf16(af[i], bfr[j], acc[i][j], 0, 0, 0);
    }

    // Epilogue: C/D layout col=lane&15 (n), row=quad*4+reg (m)
#pragma unroll
    for (int i = 0; i < 4; ++i) {
        const int mbase = bm + wm + i * 16 + quad * 4;
#pragma unroll
        for (int r = 0; r < 4; ++r) {
            float* crow = C + (size_t)(mbase + r) * NDIM + bn + wn + l16;
#pragma unroll
            for (int j = 0; j < 4; ++j) crow[j * 16] = acc[i][j][r];
        }
    }
}

// ---------------------------------------------------------------------------
extern "C" void kernel_launch(void* const* d_in, const int* in_sizes, int n_in,
                              void* d_out, int out_size, void* d_ws, size_t ws_size,
                              hipStream_t stream) {
    const float* x  = (const float*)d_in[0];           // (4,2048,4096) fp32
    const int*   w  = (const int*)d_in[1];             // (11008,4096) int (int8 values)
    const float* sz = (const float*)d_in[2];           // (32,11008,2) fp32
    float* out = (float*)d_out;                        // (4,2048,11008) fp32

    unsigned short* xq = (unsigned short*)d_ws;                                  // 67,108,864 B
    unsigned short* wq = (unsigned short*)((char*)d_ws + (size_t)MDIM * KDIM * 2); // +90,177,536 B

    quant_x_kernel<<<MDIM, 256, 0, stream>>>(x, xq);
    dequant_w_kernel<<<(NDIM * KDIM / 4) / 256, 256, 0, stream>>>(w, sz, wq);
    gemm_bt_kernel<<<dim3(NDIM / 128, MDIM / 128), 256, 0, stream>>>(xq, wq, out);
}

// Round 2
// 1545.369 us; speedup vs baseline: 1.1019x; 1.1019x over previous
//
#include <hip/hip_runtime.h>
#include <stdint.h>

// Problem constants (B=4, S=2048, K=4096, O=11008, G=128)
#define MDIM 8192   // B*S
#define NDIM 11008  // O
#define KDIM 4096   // K
#define GRP  128
#define NBLK (NDIM / 128)   // 86
#define MBLK (MDIM / 128)   // 64
#define PANEL 16            // m-block rows per L3-locality panel

typedef __attribute__((ext_vector_type(8))) __bf16 bf16x8;
typedef __attribute__((ext_vector_type(4))) float f32x4;
typedef __attribute__((ext_vector_type(4))) unsigned short u16x4;

static __device__ __forceinline__ unsigned short f2bf(float f) {
    // round-to-nearest-even fp32 -> bf16 (no NaN inputs in this problem)
    union { float f; unsigned int u; } c; c.f = f;
    unsigned int u = c.u;
    u += 0x7fffu + ((u >> 16) & 1u);
    return (unsigned short)(u >> 16);
}

// ---------------------------------------------------------------------------
// Kernel 1: dynamic per-row activation quant -> dequantized bf16
// one block (256 thr) per row of x (8192 rows, K=4096; 16 elems/thread)
// ---------------------------------------------------------------------------
__global__ __launch_bounds__(256) void quant_x_kernel(const float* __restrict__ x,
                                                      unsigned short* __restrict__ xq) {
    __shared__ float red[256];
    const int row = blockIdx.x;
    const int tid = threadIdx.x;
    const float* xr = x + (size_t)row * KDIM;

    f32x4 v[4];
    float amax = 0.f;
#pragma unroll
    for (int i = 0; i < 4; ++i) {
        v[i] = *(const f32x4*)(xr + 4 * (tid + 256 * i));
        amax = fmaxf(amax, fmaxf(fmaxf(fabsf(v[i].x), fabsf(v[i].y)),
                                 fmaxf(fabsf(v[i].z), fabsf(v[i].w))));
    }
    red[tid] = amax;
    __syncthreads();
    for (int s = 128; s > 0; s >>= 1) {
        if (tid < s) red[tid] = fmaxf(red[tid], red[tid + s]);
        __syncthreads();
    }
    const float scale = fmaxf(red[0], 1e-5f) / 127.0f;  // matches ref: max(amax,1e-5)/127

#pragma unroll
    for (int i = 0; i < 4; ++i) {
        u16x4 ov;
        float q;
        q = fminf(fmaxf(rintf(v[i].x / scale), -128.f), 127.f); ov.x = f2bf(q * scale);
        q = fminf(fmaxf(rintf(v[i].y / scale), -128.f), 127.f); ov.y = f2bf(q * scale);
        q = fminf(fmaxf(rintf(v[i].z / scale), -128.f), 127.f); ov.z = f2bf(q * scale);
        q = fminf(fmaxf(rintf(v[i].w / scale), -128.f), 127.f); ov.w = f2bf(q * scale);
        *(u16x4*)(xq + (size_t)row * KDIM + 4 * (tid + 256 * i)) = ov;
    }
}

// ---------------------------------------------------------------------------
// Kernel 2: int4-group weight dequant -> bf16 (O x K row-major = B^T layout)
// one thread per 4 consecutive k of one o. scales_and_zeros: (K/G, O, 2)
// ---------------------------------------------------------------------------
__global__ __launch_bounds__(256) void dequant_w_kernel(const int* __restrict__ w,
                                                        const float* __restrict__ sz,
                                                        unsigned short* __restrict__ wq) {
    const int idx = blockIdx.x * 256 + threadIdx.x;
    const int kc = idx & (KDIM / 4 - 1);  // 0..1023
    const int o  = idx >> 10;
    const int k0 = kc << 2;
    const int g  = k0 >> 7;               // k0 / 128
    const float2 szv = *(const float2*)(sz + ((size_t)g * NDIM + o) * 2);
    const float s = szv.x, z = szv.y;
    const int4 wv = *(const int4*)(w + (size_t)o * KDIM + k0);
    u16x4 ov;
    ov.x = f2bf(((float)wv.x - z) * s);
    ov.y = f2bf(((float)wv.y - z) * s);
    ov.z = f2bf(((float)wv.z - z) * s);
    ov.w = f2bf(((float)wv.w - z) * s);
    *(u16x4*)(wq + (size_t)o * KDIM + k0) = ov;
}

// ---------------------------------------------------------------------------
// Kernel 3: bf16 GEMM, C[M,N] = A[M,K] * B[N,K]^T  (m97 structure +
//  - panel block-swizzle for L3 locality (PANEL m-rows, m-fastest)
//  - XOR LDS chunk swizzle: row r k-chunk q stored at pos q^((r>>1)&3)
//    -> MFMA frag ds_read_b128 goes 8-way -> 2-way bank aliasing (free)
// 128x128 tile, BK=32, 256 thr = 4 waves in 2x2, each wave 64x64 via 4x4
// mfma_f32_16x16x32_bf16 frags. global_load_lds width-16 staging.
// ---------------------------------------------------------------------------
__global__ __launch_bounds__(256) void gemm_bt_kernel(const unsigned short* __restrict__ A,
                                                      const unsigned short* __restrict__ B,
                                                      float* __restrict__ C) {
    __shared__ unsigned short As[128 * 32];  // [m][k-chunk perm] 8 KB
    __shared__ unsigned short Bs[128 * 32];

    const int tid  = threadIdx.x;
    const int lane = tid & 63;
    const int wave = tid >> 6;
    const int quad = lane >> 4;
    const int l16  = lane & 15;

    // Panel swizzle: linear block id -> (m,n), m-fastest within PANEL m-rows.
    const int lid   = blockIdx.y * NBLK + blockIdx.x;       // 0..5503
    const int pb    = PANEL * NBLK;                          // 1376
    const int panel = lid / pb;
    const int rem   = lid - panel * pb;
    const int n_idx = rem >> 4;          // rem / PANEL
    const int m_idx = rem & (PANEL - 1);
    const int bm = (panel * PANEL + m_idx) * 128;
    const int bn = n_idx * 128;

    const int wm = (wave >> 1) * 64;
    const int wn = (wave & 1) * 64;

    f32x4 acc[4][4];
#pragma unroll
    for (int i = 0; i < 4; ++i)
#pragma unroll
        for (int j = 0; j < 4; ++j) acc[i][j] = (f32x4){0.f, 0.f, 0.f, 0.f};

    // Staging: tile = 512 chunks of 16B; thread t owns chunks t and t+256.
    // LDS chunk c (byte offset c*16) holds global (row=c>>2, kchunk = (c&3)^((row>>1)&3)).
    // LDS dest stays lane-contiguous (wave-uniform base + lane*16)  -- required.
    const int rlo = tid >> 2;                                  // 0..63
    const int kof = ((tid & 3) ^ ((rlo >> 1) & 3)) * 8;        // permuted global k-chunk
    // (row+64 has the same (row>>1)&3, so chunks t and t+256 share kof)
    const unsigned short* gA0 = A + (size_t)(bm + rlo) * KDIM + kof;
    const unsigned short* gA1 = A + (size_t)(bm + 64 + rlo) * KDIM + kof;
    const unsigned short* gB0 = B + (size_t)(bn + rlo) * KDIM + kof;
    const unsigned short* gB1 = B + (size_t)(bn + 64 + rlo) * KDIM + kof;
    unsigned short* lA0 = As + tid * 8;
    unsigned short* lA1 = As + (tid + 256) * 8;
    unsigned short* lB0 = Bs + tid * 8;
    unsigned short* lB1 = Bs + (tid + 256) * 8;

    // Reader-side swizzle: frag row = base + l16 with base%16==0, so
    // (row>>1)&3 == (l16>>1)&3 -> one swizzled chunk index for all frags.
    const int sw = (quad ^ ((l16 >> 1) & 3)) * 8;

    for (int k0 = 0; k0 < KDIM; k0 += 32) {
        __syncthreads();
        __builtin_amdgcn_global_load_lds((const __attribute__((address_space(1))) void*)(gA0 + k0),
                                         (__attribute__((address_space(3))) void*)lA0, 16, 0, 0);
        __builtin_amdgcn_global_load_lds((const __attribute__((address_space(1))) void*)(gA1 + k0),
                                         (__attribute__((address_space(3))) void*)lA1, 16, 0, 0);
        __builtin_amdgcn_global_load_lds((const __attribute__((address_space(1))) void*)(gB0 + k0),
                                         (__attribute__((address_space(3))) void*)lB0, 16, 0, 0);
        __builtin_amdgcn_global_load_lds((const __attribute__((address_space(1))) void*)(gB1 + k0),
                                         (__attribute__((address_space(3))) void*)lB1, 16, 0, 0);
        __syncthreads();

        bf16x8 af[4], bfr[4];
#pragma unroll
        for (int i = 0; i < 4; ++i)
            af[i] = *(const bf16x8*)(As + (wm + i * 16 + l16) * 32 + sw);
#pragma unroll
        for (int j = 0; j < 4; ++j)
            bfr[j] = *(const bf16x8*)(Bs + (wn + j * 16 + l16) * 32 + sw);

#pragma unroll
        for (int i = 0; i < 4; ++i)
#pragma unroll
            for (int j = 0; j < 4; ++j)
                acc[i][j] = __builtin_amdgcn_mfma_f32_16x16x32_bf16(af[i], bfr[j], acc[i][j], 0, 0, 0);
    }

    // Epilogue: C/D layout col=lane&15 (n), row=quad*4+reg (m)
#pragma unroll
    for (int i = 0; i < 4; ++i) {
        const int mbase = bm + wm + i * 16 + quad * 4;
#pragma unroll
        for (int r = 0; r < 4; ++r) {
            float* crow = C + (size_t)(mbase + r) * NDIM + bn + wn + l16;
#pragma unroll
            for (int j = 0; j < 4; ++j) crow[j * 16] = acc[i][j][r];
        }
    }
}

// ---------------------------------------------------------------------------
extern "C" void kernel_launch(void* const* d_in, const int* in_sizes, int n_in,
                              void* d_out, int out_size, void* d_ws, size_t ws_size,
                              hipStream_t stream) {
    const float* x  = (const float*)d_in[0];           // (4,2048,4096) fp32
    const int*   w  = (const int*)d_in[1];             // (11008,4096) int (int8 values)
    const float* sz = (const float*)d_in[2];           // (32,11008,2) fp32
    float* out = (float*)d_out;                        // (4,2048,11008) fp32

    unsigned short* xq = (unsigned short*)d_ws;                                    // 67,108,864 B
    unsigned short* wq = (unsigned short*)((char*)d_ws + (size_t)MDIM * KDIM * 2); // +90,177,536 B

    quant_x_kernel<<<MDIM, 256, 0, stream>>>(x, xq);
    dequant_w_kernel<<<(NDIM * KDIM / 4) / 256, 256, 0, stream>>>(w, sz, wq);
    gemm_bt_kernel<<<dim3(NBLK, MBLK), 256, 0, stream>>>(xq, wq, out);
}